// Round 6
// baseline (161.058 us; speedup 1.0000x reference)
//
#include <hip/hip_runtime.h>
#include <math.h>

#define NB     8
#define BATCH  64
#define FEAT   512
#define WHALF  513                 // W/2 + 1
#define PIX    (1024 * 513)        // 525312
#define MAX_R  0x1.6A09E6p-1f      // sqrtf(0.5f) == reference radius.max()

typedef float vfloat4 __attribute__((ext_vector_type(4)));

// ---------------------------------------------------------------------------
// Band classification, bit-exact vs the numpy reference (verified r1/r3/r4/r5):
//   r2 = u*u + v*v is EXACT in f32 (k^2 + l^2 <= 2^19 fits the mantissa),
//   sqrtf is correctly rounded, boundaries use the identical f32 expression
//   max_r * (i/8).  Returns 8 for the single r == max_r pixel (-> weight 0).
// ---------------------------------------------------------------------------
__device__ __forceinline__ int band_of(int p) {
    const int h  = p / WHALF;
    const int wp = p - h * WHALF;
    const float u = (float)wp * 0.0009765625f;                  // wp / 1024, exact
    const int hv  = (h >= 512) ? (h - 1024) : h;                // fftfreq numerator
    const float v = (float)hv * 0.0009765625f;                  // exact
    const float r = sqrtf(fmaf(u, u, v * v));                   // r2 exact -> r CR

    int j = (int)(r * (8.0f / MAX_R));                          // estimate
    if (j > 8) j = 8;
    const float lo = MAX_R * ((float)j * 0.125f);               // == ref lower[j]
    if (r < lo) {
        --j;
    } else if (j < 8) {
        const float hi = MAX_R * ((float)(j + 1) * 0.125f);     // == ref upper[j]
        if (r >= hi) ++j;
    }
    return j;                                                   // 0..7, or 8 = none
}

// ---------------------------------------------------------------------------
// K1: bw[b][n] = softmax(ff[b] @ w.T + bias) -> ws, computed once (r4 showed
// per-writer-block recompute costs ~1 GB of L2 reads and 3x the time).
// ---------------------------------------------------------------------------
__global__ void bw_kernel(const float* __restrict__ ff,
                          const float* __restrict__ w,
                          const float* __restrict__ bias,
                          float* __restrict__ bw) {
    const int b = blockIdx.x;      // one block per batch row
    const int t = threadIdx.x;     // 256 threads

    float part[NB];
#pragma unroll
    for (int n = 0; n < NB; ++n) part[n] = 0.0f;

    for (int k = t; k < FEAT; k += 256) {
        const float f = ff[b * FEAT + k];
#pragma unroll
        for (int n = 0; n < NB; ++n) part[n] += f * w[n * FEAT + k];
    }

#pragma unroll
    for (int n = 0; n < NB; ++n) {
#pragma unroll
        for (int off = 32; off > 0; off >>= 1)
            part[n] += __shfl_down(part[n], off);
    }

    __shared__ float red[4][NB];
    const int wave = t >> 6, lane = t & 63;
    if (lane == 0) {
#pragma unroll
        for (int n = 0; n < NB; ++n) red[wave][n] = part[n];
    }
    __syncthreads();

    if (t == 0) {
        float logit[NB], m = -1e30f;
#pragma unroll
        for (int n = 0; n < NB; ++n) {
            logit[n] = red[0][n] + red[1][n] + red[2][n] + red[3][n] + bias[n];
            m = fmaxf(m, logit[n]);
        }
        float s = 0.0f;
#pragma unroll
        for (int n = 0; n < NB; ++n) { logit[n] = expf(logit[n] - m); s += logit[n]; }
        const float inv = 1.0f / s;
#pragma unroll
        for (int n = 0; n < NB; ++n) bw[b * NB + n] = logit[n] * inv;
    }
}

// ---------------------------------------------------------------------------
// K2: grid (513 chunks, 64 batches); each block owns ONE contiguous 4 KB
// span of ONE batch plane. Consecutive blockIdx.x -> linear output sweep,
// the same store stream as the 6.2 TB/s fill kernel. Per block: one cache
// line of weights into a 9-entry padded LDS table (same-address broadcast
// reads), 4 inline band_of (~free, r4: VALUBusy 12.9%), 1 nontemporal
// float4 store per thread.
// ---------------------------------------------------------------------------
__global__ void __launch_bounds__(256)
out_kernel(const float* __restrict__ bw, float* __restrict__ out) {
    const int t     = threadIdx.x;
    const int chunk = blockIdx.x;                // 0..512
    const int b     = blockIdx.y;                // 0..63

    __shared__ float sbw[9];                     // 8 weights + 0-pad for band 8
    if (t < 9) sbw[t] = (t < NB) ? bw[b * NB + t] : 0.0f;
    __syncthreads();

    const int p  = chunk * 1024 + t * 4;
    const int j0 = band_of(p + 0);
    const int j1 = band_of(p + 1);
    const int j2 = band_of(p + 2);
    const int j3 = band_of(p + 3);

    vfloat4 v;
    v.x = sbw[j0];
    v.y = sbw[j1];
    v.z = sbw[j2];
    v.w = sbw[j3];
    __builtin_nontemporal_store(
        v, reinterpret_cast<vfloat4*>(out + (size_t)b * PIX + p));
}

extern "C" void kernel_launch(void* const* d_in, const int* in_sizes, int n_in,
                              void* d_out, int out_size, void* d_ws, size_t ws_size,
                              hipStream_t stream) {
    const float* ff   = (const float*)d_in[0];   // [64, 512]
    const float* w    = (const float*)d_in[1];   // [8, 512]
    const float* bias = (const float*)d_in[2];   // [8]
    float* out = (float*)d_out;                  // [64, 1, 1024, 513] f32

    float* bw = (float*)d_ws;                    // 2048 B of the workspace

    bw_kernel<<<BATCH, 256, 0, stream>>>(ff, w, bias, bw);
    out_kernel<<<dim3(513, 64), 256, 0, stream>>>(bw, out);
}